// Round 2
// baseline (145.141 us; speedup 1.0000x reference)
//
#include <hip/hip_runtime.h>

typedef unsigned short u16;
typedef unsigned int u32;
typedef unsigned long long u64;
typedef __attribute__((ext_vector_type(8))) short short8;
typedef __attribute__((ext_vector_type(4))) float f32x4;

#define BATCH 8
#define NSEQ 1024
#define DMODEL 512
#define HDIM 64
#define QK_SCALE 0.04419417382415922f

// workspace byte offsets
#define O_QBF 0ULL
#define O_KBF 8388608ULL
#define O_WB  16777216ULL
#define O_MB  18874368ULL
#define O_QP  19922944ULL
#define O_KP  28311552ULL
#define O_VP  36700160ULL

__device__ __forceinline__ u16 f2bf(float f) {
  u32 u = __float_as_uint(f);
  u = (u + 0x7fffu + ((u >> 16) & 1u)) >> 16;
  return (u16)u;
}
__device__ __forceinline__ float bf2f(u16 s) {
  return __uint_as_float(((u32)s) << 16);
}
__device__ __forceinline__ void gload16(const void* g, void* l) {
  __builtin_amdgcn_global_load_lds((const __attribute__((address_space(1))) void*)g,
                                   (__attribute__((address_space(3))) void*)l, 16, 0, 0);
}

// ---------------------------------------------------------------------------
// prep: fp32->bf16 Q/K, transpose-convert weights to [N][K], pack M to bits
// ---------------------------------------------------------------------------
__global__ __launch_bounds__(256) void prep_kernel(
    const float* __restrict__ Q, const float* __restrict__ K,
    const float* __restrict__ Wq, const float* __restrict__ Wk,
    const float* __restrict__ Wv, const float* __restrict__ Wo,
    const int* __restrict__ M,
    u16* __restrict__ Qbf, u16* __restrict__ Kbf, u16* __restrict__ Wb,
    u64* __restrict__ Mb)
{
  __shared__ float lds[64 * 68];
  const int bi = blockIdx.x, t = threadIdx.x;
  if (bi < 4096) {
    const float* src = (bi < 2048) ? Q : K;
    u16* dst = (bi < 2048) ? Qbf : Kbf;
    const int lb = bi & 2047;
    const size_t base = ((size_t)lb * 256 + t) * 8;
    float4 a = *(const float4*)(src + base);
    float4 c = *(const float4*)(src + base + 4);
    short8 o;
    o[0] = (short)f2bf(a.x); o[1] = (short)f2bf(a.y);
    o[2] = (short)f2bf(a.z); o[3] = (short)f2bf(a.w);
    o[4] = (short)f2bf(c.x); o[5] = (short)f2bf(c.y);
    o[6] = (short)f2bf(c.z); o[7] = (short)f2bf(c.w);
    *(short8*)(dst + base) = o;
  } else if (bi < 4352) {
    const int qid = bi - 4096;
    const int w = qid >> 6;
    const int tt = qid & 63;
    const int tr = tt >> 3, tc = tt & 7;          // 64x64 tile at (tr*64 k, tc*64 n)
    const float* W = (w == 0) ? Wq : (w == 1) ? Wk : (w == 2) ? Wv : Wo;
#pragma unroll
    for (int j = 0; j < 4; ++j) {
      int vi = j * 256 + t;
      int row = vi >> 4, c4 = vi & 15;
      float4 v = *(const float4*)(W + (size_t)(tr * 64 + row) * 512 + tc * 64 + c4 * 4);
      lds[row * 68 + c4 * 4 + 0] = v.x;
      lds[row * 68 + c4 * 4 + 1] = v.y;
      lds[row * 68 + c4 * 4 + 2] = v.z;
      lds[row * 68 + c4 * 4 + 3] = v.w;
    }
    __syncthreads();
    // 64 n-rows x 8 k8-chunks = 512 short8 stores -> exactly 2 iterations of 256
    // (j<4 here was the round-1 bug: oi>=512 gave nl in [64,128) -> OOB garbage
    //  writes that corrupted Wb rows and spilled past Wb into the Mb mask region)
#pragma unroll
    for (int j = 0; j < 2; ++j) {
      int oi = j * 256 + t;
      int nl = oi >> 3, k8 = oi & 7;
      short8 o;
#pragma unroll
      for (int i = 0; i < 8; ++i) o[i] = (short)f2bf(lds[(k8 * 8 + i) * 68 + nl]);
      *(short8*)(Wb + (size_t)w * 262144 + (size_t)(tc * 64 + nl) * 512 + tr * 64 + k8 * 8) = o;
    }
  } else {
    const int pb = bi - 4352;
    const int wv = t >> 6, lane = t & 63;
    for (int i = 0; i < 32; ++i) {
      int widx = pb * 128 + wv * 32 + i;          // < 131072
      int kc = widx & 15;
      int qq = (widx >> 4) & 1023;
      int bb = widx >> 14;
      int mv = M[((size_t)bb * 1024 + qq) * 1024 + kc * 64 + lane];
      u64 bal = __ballot(mv != 0);
      if (lane == 0) Mb[widx] = bal;
    }
  }
}

// ---------------------------------------------------------------------------
// gemm_bt: C[M=8192,N=512] = A[M,512] * Wb^T (Wb stored [N][K]) + bias
// MODE 0: store bf16 (3 outputs via blockIdx.z)  MODE 1: relu+residual
// 128x128 tile, BK=32, 4 waves, m97 2-barrier structure with global_load_lds
// ---------------------------------------------------------------------------
template<int MODE>
__global__ __launch_bounds__(256) void gemm_bt(
    const u16* __restrict__ Aq, const u16* __restrict__ Ak,
    const u16* __restrict__ Wb,
    const float* __restrict__ b0, const float* __restrict__ b1, const float* __restrict__ b2,
    u16* __restrict__ outp, const u16* __restrict__ resid)
{
  __shared__ __align__(16) char Alds[8192];
  __shared__ __align__(16) char Blds[8192];
  const int tid = threadIdx.x;
  const int wv = tid >> 6, lane = tid & 63;
  const int g16 = lane >> 4, l16 = lane & 15;
  const int wr = wv >> 1, wc = wv & 1;
  const int bx = blockIdx.x, by = blockIdx.y, bz = blockIdx.z;

  const u16* A; const u16* W; const float* bias; u16* out;
  if (MODE == 0) {
    A = (bz == 0) ? Aq : Ak;
    W = Wb + (size_t)bz * 262144;
    bias = (bz == 0) ? b0 : ((bz == 1) ? b1 : b2);
    out = outp + (size_t)bz * 4194304;
  } else {
    A = Aq; W = Wb; bias = b0; out = outp;
  }

  const int m0 = bx * 128, n0 = by * 128;
  f32x4 acc[4][4] = {};

  for (int kt = 0; kt < 16; ++kt) {
    const int k0 = kt * 32;
#pragma unroll
    for (int r = 0; r < 2; ++r) {
      int idx = r * 256 + tid;
      int row = idx >> 2, sl = idx & 3;
      gload16(A + (size_t)(m0 + row) * 512 + k0 + sl * 8, Alds + r * 4096 + wv * 1024);
      gload16(W + (size_t)(n0 + row) * 512 + k0 + sl * 8, Blds + r * 4096 + wv * 1024);
    }
    __syncthreads();
    short8 af[4], bfr[4];
#pragma unroll
    for (int mt = 0; mt < 4; ++mt)
      af[mt] = *(const short8*)(Alds + (wr * 64 + mt * 16 + l16) * 64 + g16 * 16);
#pragma unroll
    for (int nt = 0; nt < 4; ++nt)
      bfr[nt] = *(const short8*)(Blds + (wc * 64 + nt * 16 + l16) * 64 + g16 * 16);
#pragma unroll
    for (int mt = 0; mt < 4; ++mt)
#pragma unroll
      for (int nt = 0; nt < 4; ++nt)
        acc[mt][nt] = __builtin_amdgcn_mfma_f32_16x16x32_bf16(af[mt], bfr[nt], acc[mt][nt], 0, 0, 0);
    __syncthreads();
  }

#pragma unroll
  for (int nt = 0; nt < 4; ++nt) {
    int col = n0 + wc * 64 + nt * 16 + l16;
    float bcol = bias[col];
#pragma unroll
    for (int mt = 0; mt < 4; ++mt) {
#pragma unroll
      for (int r = 0; r < 4; ++r) {
        int row = m0 + wr * 64 + mt * 16 + g16 * 4 + r;
        float v = acc[mt][nt][r] + bcol;
        if (MODE == 1) {
          v = fmaxf(v, 0.f) + bf2f(resid[(size_t)row * 512 + col]);
        }
        out[(size_t)row * 512 + col] = f2bf(v);
      }
    }
  }
}

// ---------------------------------------------------------------------------
// flash attention: block = (b, h, 128 q rows), 4 waves x 32 rows, KBLK=64
// O1 = Qh + softmax(mask(Q K^T / sqrt(512))) V   (per-head)
// ---------------------------------------------------------------------------
__global__ __launch_bounds__(256) void attn_kernel(
    const u16* __restrict__ Qp, const u16* __restrict__ Kp, const u16* __restrict__ Vp,
    const u64* __restrict__ Mb, u16* __restrict__ O1)
{
  __shared__ __align__(16) char K_lds[8192];     // [64 k][64 dk] bf16, slot-swizzled
  __shared__ __align__(16) char VT_lds[8192];    // [64 dv][64 k] bf16, slot-swizzled
  __shared__ __align__(16) char P_lds[4][4096];  // per-wave [32 q][64 k] bf16, swizzled

  const int tid = threadIdx.x;
  const int wv = tid >> 6, lane = tid & 63;
  const int g16 = lane >> 4, l16 = lane & 15;
  const int qt = blockIdx.x, h = blockIdx.y, b = blockIdx.z;
  const int qg = qt * 128;
  const int hb = h * HDIM;
  const size_t batch_row = (size_t)b * NSEQ;

  // hoist Q A-frags (A: row=lane&15, k=(lane>>4)*8+j)
  short8 a_q[2][2];
#pragma unroll
  for (int m = 0; m < 2; ++m)
#pragma unroll
    for (int kk = 0; kk < 2; ++kk) {
      int qrow = qg + wv * 32 + m * 16 + l16;
      a_q[m][kk] = *(const short8*)(Qp + (batch_row + qrow) * DMODEL + hb + kk * 32 + g16 * 8);
    }

  float mM[2][4], lL[2][4];
  f32x4 accO[2][4] = {};
#pragma unroll
  for (int m = 0; m < 2; ++m)
#pragma unroll
    for (int r = 0; r < 4; ++r) { mM[m][r] = -1e30f; lL[m][r] = 0.f; }

  char* Pw = &P_lds[wv][0];

  for (int kt = 0; kt < 16; ++kt) {
    // stage K tile via global_load_lds, linear dest + inverse-swizzled source
#pragma unroll
    for (int r = 0; r < 2; ++r) {
      int idx = r * 256 + tid;
      int row = idx >> 3, sl = idx & 7;
      int chunk = sl ^ (row & 7);
      gload16(Kp + (batch_row + kt * 64 + row) * DMODEL + hb + chunk * 8,
              K_lds + r * 4096 + wv * 1024);
    }
    // stage V^T: coalesced 4B global loads, swizzled b128 LDS writes
    {
      int dv2 = (tid & 31) * 2;
      int kg = tid >> 5;                         // 0..7
      short8 slo, shi;
#pragma unroll
      for (int j = 0; j < 8; ++j) {
        u32 u = *(const u32*)(Vp + (batch_row + kt * 64 + kg * 8 + j) * DMODEL + hb + dv2);
        slo[j] = (short)(u & 0xffffu);
        shi[j] = (short)(u >> 16);
      }
      *(short8*)(VT_lds + dv2 * 128 + ((kg ^ (dv2 & 7)) << 4)) = slo;
      *(short8*)(VT_lds + (dv2 + 1) * 128 + ((kg ^ ((dv2 + 1) & 7)) << 4)) = shi;
    }
    __syncthreads();

    // S = Q K^T  (B: col=lane&15 -> k-local, k-dim = dk)
    f32x4 s_[2][4];
#pragma unroll
    for (int nt = 0; nt < 4; ++nt) {
      int row = nt * 16 + l16;
      short8 bk0 = *(const short8*)(K_lds + row * 128 + ((g16 ^ (row & 7)) << 4));
      short8 bk1 = *(const short8*)(K_lds + row * 128 + (((4 + g16) ^ (row & 7)) << 4));
#pragma unroll
      for (int m = 0; m < 2; ++m) {
        f32x4 acc = {0.f, 0.f, 0.f, 0.f};
        acc = __builtin_amdgcn_mfma_f32_16x16x32_bf16(a_q[m][0], bk0, acc, 0, 0, 0);
        acc = __builtin_amdgcn_mfma_f32_16x16x32_bf16(a_q[m][1], bk1, acc, 0, 0, 0);
        s_[m][nt] = acc;
      }
    }

    // online softmax (wave-parallel: reduce over lane&15 via shfl_xor)
#pragma unroll
    for (int m = 0; m < 2; ++m) {
#pragma unroll
      for (int r = 0; r < 4; ++r) {
        int qloc = m * 16 + g16 * 4 + r;
        int q = qg + wv * 32 + qloc;
        u64 mk = Mb[(batch_row + q) * 16 + kt];
        float v4[4];
        u32 bits = 0;
        float mx = -1e30f;
#pragma unroll
        for (int nt = 0; nt < 4; ++nt) {
          u32 bit = (u32)((mk >> (nt * 16 + l16)) & 1ULL);
          float val = s_[m][nt][r] * QK_SCALE;
          if (!bit) val = -1e30f; else bits |= (1u << nt);
          v4[nt] = val;
          mx = fmaxf(mx, val);
        }
        mx = fmaxf(mx, __shfl_xor(mx, 1, 64));
        mx = fmaxf(mx, __shfl_xor(mx, 2, 64));
        mx = fmaxf(mx, __shfl_xor(mx, 4, 64));
        mx = fmaxf(mx, __shfl_xor(mx, 8, 64));
        float nm = fmaxf(mM[m][r], mx);
        float corr = __expf(mM[m][r] - nm);
        mM[m][r] = nm;
        float sum = 0.f;
#pragma unroll
        for (int nt = 0; nt < 4; ++nt) {
          float e = ((bits >> nt) & 1u) ? __expf(v4[nt] - nm) : 0.f;
          v4[nt] = e;
          sum += e;
        }
        sum += __shfl_xor(sum, 1, 64);
        sum += __shfl_xor(sum, 2, 64);
        sum += __shfl_xor(sum, 4, 64);
        sum += __shfl_xor(sum, 8, 64);
        lL[m][r] = lL[m][r] * corr + sum;
#pragma unroll
        for (int dvt = 0; dvt < 4; ++dvt) accO[m][dvt][r] *= corr;
        // write P (bf16) into per-wave swizzled LDS
#pragma unroll
        for (int nt = 0; nt < 4; ++nt) {
          int kl = nt * 16 + l16;
          int byt = kl * 2;
          int ph = (((byt >> 4) ^ (qloc & 7)) << 4) | (byt & 15);
          *(u16*)(Pw + qloc * 128 + ph) = f2bf(v4[nt]);
        }
      }
    }

    // PV: A = P (from wave-private LDS), B = V (from VT_lds)
    short8 a_p[2][2];
#pragma unroll
    for (int m = 0; m < 2; ++m) {
      int prow = m * 16 + l16;
      a_p[m][0] = *(const short8*)(Pw + prow * 128 + ((g16 ^ (prow & 7)) << 4));
      a_p[m][1] = *(const short8*)(Pw + prow * 128 + (((4 + g16) ^ (prow & 7)) << 4));
    }
#pragma unroll
    for (int dvt = 0; dvt < 4; ++dvt) {
      int vrow = dvt * 16 + l16;
      short8 bv0 = *(const short8*)(VT_lds + vrow * 128 + ((g16 ^ (vrow & 7)) << 4));
      short8 bv1 = *(const short8*)(VT_lds + vrow * 128 + (((4 + g16) ^ (vrow & 7)) << 4));
#pragma unroll
      for (int m = 0; m < 2; ++m) {
        accO[m][dvt] = __builtin_amdgcn_mfma_f32_16x16x32_bf16(a_p[m][0], bv0, accO[m][dvt], 0, 0, 0);
        accO[m][dvt] = __builtin_amdgcn_mfma_f32_16x16x32_bf16(a_p[m][1], bv1, accO[m][dvt], 0, 0, 0);
      }
    }
    __syncthreads();
  }

  // epilogue: O = Qh + accO / l
#pragma unroll
  for (int m = 0; m < 2; ++m)
#pragma unroll
    for (int r = 0; r < 4; ++r) {
      int q = qg + wv * 32 + m * 16 + g16 * 4 + r;
      float inv = 1.0f / fmaxf(lL[m][r], 1e-20f);
#pragma unroll
      for (int dvt = 0; dvt < 4; ++dvt) {
        int dv = hb + dvt * 16 + l16;
        size_t o = (batch_row + q) * DMODEL + dv;
        O1[o] = f2bf(accO[m][dvt][r] * inv + bf2f(Qp[o]));
      }
    }
}

// ---------------------------------------------------------------------------
// layernorm: one wave per 512-ch row. OUTF=0 -> bf16 out, OUTF=1 -> fp32 out
// ---------------------------------------------------------------------------
template<int OUTF>
__global__ __launch_bounds__(256) void ln_kernel(
    const u16* __restrict__ X, const float* __restrict__ g, const float* __restrict__ bb,
    void* __restrict__ outv)
{
  const int tid = threadIdx.x;
  const int wv = tid >> 6, lane = tid & 63;
  const size_t row = (size_t)blockIdx.x * 4 + wv;
  short8 x8 = *(const short8*)(X + row * 512 + lane * 8);
  float xf[8];
  float s = 0.f, s2 = 0.f;
#pragma unroll
  for (int i = 0; i < 8; ++i) {
    xf[i] = bf2f((u16)x8[i]);
    s += xf[i];
    s2 += xf[i] * xf[i];
  }
#pragma unroll
  for (int d = 1; d < 64; d <<= 1) {
    s += __shfl_xor(s, d, 64);
    s2 += __shfl_xor(s2, d, 64);
  }
  float mu = s * (1.f / 512.f);
  float var = s2 * (1.f / 512.f) - mu * mu;
  float rs = rsqrtf(var + 1e-5f);
  float4 ga = *(const float4*)(g + lane * 8);
  float4 gb = *(const float4*)(g + lane * 8 + 4);
  float4 ba = *(const float4*)(bb + lane * 8);
  float4 bc = *(const float4*)(bb + lane * 8 + 4);
  float gv[8] = {ga.x, ga.y, ga.z, ga.w, gb.x, gb.y, gb.z, gb.w};
  float bv[8] = {ba.x, ba.y, ba.z, ba.w, bc.x, bc.y, bc.z, bc.w};
  float y[8];
#pragma unroll
  for (int i = 0; i < 8; ++i) y[i] = (xf[i] - mu) * rs * gv[i] + bv[i];
  if (OUTF) {
    float* o = (float*)outv + row * 512 + lane * 8;
    float4 o1 = {y[0], y[1], y[2], y[3]};
    float4 o2 = {y[4], y[5], y[6], y[7]};
    *(float4*)o = o1;
    *(float4*)(o + 4) = o2;
  } else {
    short8 o;
#pragma unroll
    for (int i = 0; i < 8; ++i) o[i] = (short)f2bf(y[i]);
    *(short8*)((u16*)outv + row * 512 + lane * 8) = o;
  }
}

// ---------------------------------------------------------------------------
extern "C" void kernel_launch(void* const* d_in, const int* in_sizes, int n_in,
                              void* d_out, int out_size, void* d_ws, size_t ws_size,
                              hipStream_t stream) {
  (void)in_sizes; (void)n_in; (void)out_size; (void)ws_size;
  const float* Q  = (const float*)d_in[0];
  const float* K  = (const float*)d_in[1];
  const float* Wq = (const float*)d_in[2];
  const float* bq = (const float*)d_in[3];
  const float* Wk = (const float*)d_in[4];
  const float* bk = (const float*)d_in[5];
  const float* Wv = (const float*)d_in[6];
  const float* bv = (const float*)d_in[7];
  const float* Wo = (const float*)d_in[8];
  const float* bo = (const float*)d_in[9];
  const float* g0 = (const float*)d_in[10];
  const float* b0 = (const float*)d_in[11];
  const float* g1 = (const float*)d_in[12];
  const float* b1 = (const float*)d_in[13];
  const int*   M  = (const int*)d_in[14];
  float* out = (float*)d_out;
  char* ws = (char*)d_ws;

  u16* Qbf = (u16*)(ws + O_QBF);
  u16* Kbf = (u16*)(ws + O_KBF);
  u16* Wb  = (u16*)(ws + O_WB);
  u64* Mb  = (u64*)(ws + O_MB);
  u16* Qp  = (u16*)(ws + O_QP);
  u16* Kp  = (u16*)(ws + O_KP);
  u16* Vp  = (u16*)(ws + O_VP);
  u16* O1  = Kbf;   // Kbf dead after gemm1
  u16* Xn  = Qp;    // Qp dead after attn
  u16* Z   = Qbf;   // Qbf dead after gemm1

  prep_kernel<<<5376, 256, 0, stream>>>(Q, K, Wq, Wk, Wv, Wo, M, Qbf, Kbf, Wb, Mb);
  gemm_bt<0><<<dim3(64, 4, 3), 256, 0, stream>>>(Qbf, Kbf, Wb, bq, bk, bv, Qp, nullptr);
  attn_kernel<<<dim3(8, 8, 8), 256, 0, stream>>>(Qp, Kp, Vp, Mb, O1);
  ln_kernel<0><<<2048, 256, 0, stream>>>(O1, g0, b0, (void*)Xn);
  gemm_bt<1><<<dim3(64, 4, 1), 256, 0, stream>>>(Xn, nullptr, Wb + 3 * 262144, bo,
                                                 nullptr, nullptr, Z, Xn);
  ln_kernel<1><<<2048, 256, 0, stream>>>(Z, g1, b1, (void*)out);
}

// Round 3
// 119.188 us; speedup vs baseline: 1.2177x; 1.2177x over previous
//
#include <hip/hip_runtime.h>

typedef unsigned short u16;
typedef unsigned int u32;
typedef unsigned long long u64;
typedef __attribute__((ext_vector_type(8))) short short8;
typedef __attribute__((ext_vector_type(4))) float f32x4;

#define BATCH 8
#define NSEQ 1024
#define DMODEL 512
#define HDIM 64
#define QK_SCALE 0.04419417382415922f
// QK_SCALE * log2(e): softmax computed in exp2 domain
#define SCALE_LOG2E 0.06375871114929199f

// workspace byte offsets
#define O_QBF 0ULL
#define O_KBF 8388608ULL
#define O_WB  16777216ULL
#define O_MB  18874368ULL
#define O_QP  19922944ULL
#define O_KP  28311552ULL
#define O_VP  36700160ULL

__device__ __forceinline__ u16 f2bf(float f) {
  u32 u = __float_as_uint(f);
  u = (u + 0x7fffu + ((u >> 16) & 1u)) >> 16;
  return (u16)u;
}
__device__ __forceinline__ float bf2f(u16 s) {
  return __uint_as_float(((u32)s) << 16);
}
__device__ __forceinline__ void gload16(const void* g, void* l) {
  __builtin_amdgcn_global_load_lds((const __attribute__((address_space(1))) void*)g,
                                   (__attribute__((address_space(3))) void*)l, 16, 0, 0);
}

// ---------------------------------------------------------------------------
// prep: fp32->bf16 Q/K, transpose-convert weights to [N][K], pack M to bits
// ---------------------------------------------------------------------------
__global__ __launch_bounds__(256) void prep_kernel(
    const float* __restrict__ Q, const float* __restrict__ K,
    const float* __restrict__ Wq, const float* __restrict__ Wk,
    const float* __restrict__ Wv, const float* __restrict__ Wo,
    const int* __restrict__ M,
    u16* __restrict__ Qbf, u16* __restrict__ Kbf, u16* __restrict__ Wb,
    u64* __restrict__ Mb)
{
  __shared__ float lds[64 * 68];
  const int bi = blockIdx.x, t = threadIdx.x;
  if (bi < 4096) {
    const float* src = (bi < 2048) ? Q : K;
    u16* dst = (bi < 2048) ? Qbf : Kbf;
    const int lb = bi & 2047;
    const size_t base = ((size_t)lb * 256 + t) * 8;
    float4 a = *(const float4*)(src + base);
    float4 c = *(const float4*)(src + base + 4);
    short8 o;
    o[0] = (short)f2bf(a.x); o[1] = (short)f2bf(a.y);
    o[2] = (short)f2bf(a.z); o[3] = (short)f2bf(a.w);
    o[4] = (short)f2bf(c.x); o[5] = (short)f2bf(c.y);
    o[6] = (short)f2bf(c.z); o[7] = (short)f2bf(c.w);
    *(short8*)(dst + base) = o;
  } else if (bi < 4352) {
    const int qid = bi - 4096;
    const int w = qid >> 6;
    const int tt = qid & 63;
    const int tr = tt >> 3, tc = tt & 7;          // 64x64 tile at (tr*64 k, tc*64 n)
    const float* W = (w == 0) ? Wq : (w == 1) ? Wk : (w == 2) ? Wv : Wo;
#pragma unroll
    for (int j = 0; j < 4; ++j) {
      int vi = j * 256 + t;
      int row = vi >> 4, c4 = vi & 15;
      float4 v = *(const float4*)(W + (size_t)(tr * 64 + row) * 512 + tc * 64 + c4 * 4);
      lds[row * 68 + c4 * 4 + 0] = v.x;
      lds[row * 68 + c4 * 4 + 1] = v.y;
      lds[row * 68 + c4 * 4 + 2] = v.z;
      lds[row * 68 + c4 * 4 + 3] = v.w;
    }
    __syncthreads();
    // 64 n-rows x 8 k8-chunks = 512 short8 stores -> exactly 2 iterations of 256
#pragma unroll
    for (int j = 0; j < 2; ++j) {
      int oi = j * 256 + t;
      int nl = oi >> 3, k8 = oi & 7;
      short8 o;
#pragma unroll
      for (int i = 0; i < 8; ++i) o[i] = (short)f2bf(lds[(k8 * 8 + i) * 68 + nl]);
      *(short8*)(Wb + (size_t)w * 262144 + (size_t)(tc * 64 + nl) * 512 + tr * 64 + k8 * 8) = o;
    }
  } else {
    const int pb = bi - 4352;
    const int wv = t >> 6, lane = t & 63;
    for (int i = 0; i < 32; ++i) {
      int widx = pb * 128 + wv * 32 + i;          // < 131072
      int kc = widx & 15;
      int qq = (widx >> 4) & 1023;
      int bb = widx >> 14;
      int mv = M[((size_t)bb * 1024 + qq) * 1024 + kc * 64 + lane];
      u64 bal = __ballot(mv != 0);
      if (lane == 0) Mb[widx] = bal;
    }
  }
}

// ---------------------------------------------------------------------------
// gemm_bt: C[M=8192,N=512] = A[M,512] * Wb^T (Wb stored [N][K]) + bias
// ---------------------------------------------------------------------------
template<int MODE>
__global__ __launch_bounds__(256) void gemm_bt(
    const u16* __restrict__ Aq, const u16* __restrict__ Ak,
    const u16* __restrict__ Wb,
    const float* __restrict__ b0, const float* __restrict__ b1, const float* __restrict__ b2,
    u16* __restrict__ outp, const u16* __restrict__ resid)
{
  __shared__ __align__(16) char Alds[8192];
  __shared__ __align__(16) char Blds[8192];
  const int tid = threadIdx.x;
  const int wv = tid >> 6, lane = tid & 63;
  const int g16 = lane >> 4, l16 = lane & 15;
  const int wr = wv >> 1, wc = wv & 1;
  const int bx = blockIdx.x, by = blockIdx.y, bz = blockIdx.z;

  const u16* A; const u16* W; const float* bias; u16* out;
  if (MODE == 0) {
    A = (bz == 0) ? Aq : Ak;
    W = Wb + (size_t)bz * 262144;
    bias = (bz == 0) ? b0 : ((bz == 1) ? b1 : b2);
    out = outp + (size_t)bz * 4194304;
  } else {
    A = Aq; W = Wb; bias = b0; out = outp;
  }

  const int m0 = bx * 128, n0 = by * 128;
  f32x4 acc[4][4] = {};

  for (int kt = 0; kt < 16; ++kt) {
    const int k0 = kt * 32;
#pragma unroll
    for (int r = 0; r < 2; ++r) {
      int idx = r * 256 + tid;
      int row = idx >> 2, sl = idx & 3;
      gload16(A + (size_t)(m0 + row) * 512 + k0 + sl * 8, Alds + r * 4096 + wv * 1024);
      gload16(W + (size_t)(n0 + row) * 512 + k0 + sl * 8, Blds + r * 4096 + wv * 1024);
    }
    __syncthreads();
    short8 af[4], bfr[4];
#pragma unroll
    for (int mt = 0; mt < 4; ++mt)
      af[mt] = *(const short8*)(Alds + (wr * 64 + mt * 16 + l16) * 64 + g16 * 16);
#pragma unroll
    for (int nt = 0; nt < 4; ++nt)
      bfr[nt] = *(const short8*)(Blds + (wc * 64 + nt * 16 + l16) * 64 + g16 * 16);
#pragma unroll
    for (int mt = 0; mt < 4; ++mt)
#pragma unroll
      for (int nt = 0; nt < 4; ++nt)
        acc[mt][nt] = __builtin_amdgcn_mfma_f32_16x16x32_bf16(af[mt], bfr[nt], acc[mt][nt], 0, 0, 0);
    __syncthreads();
  }

#pragma unroll
  for (int nt = 0; nt < 4; ++nt) {
    int col = n0 + wc * 64 + nt * 16 + l16;
    float bcol = bias[col];
#pragma unroll
    for (int mt = 0; mt < 4; ++mt) {
#pragma unroll
      for (int r = 0; r < 4; ++r) {
        int row = m0 + wr * 64 + mt * 16 + g16 * 4 + r;
        float v = acc[mt][nt][r] + bcol;
        if (MODE == 1) {
          v = fmaxf(v, 0.f) + bf2f(resid[(size_t)row * 512 + col]);
        }
        out[(size_t)row * 512 + col] = f2bf(v);
      }
    }
  }
}

// ---------------------------------------------------------------------------
// flash attention, swapped-operand form. Block = 64 q rows, 4 waves x 16 q.
//   S^T[k][q] = mfma(A=K, B=Q)  -> lane owns q = lane&15, k lane-local
//   O^T[dv][q] = mfma(A=V^T, B=P^T)
// Grid 1024 blocks, XCD-swizzled so all q-tiles of one (b,h) share an XCD L2.
// ---------------------------------------------------------------------------
__global__ __launch_bounds__(256) void attn_kernel(
    const u16* __restrict__ Qp, const u16* __restrict__ Kp, const u16* __restrict__ Vp,
    const u64* __restrict__ Mb, u16* __restrict__ O1)
{
  __shared__ __align__(16) char K_lds[8192];     // [64 k][64 dk] bf16, chunk-swizzled
  __shared__ __align__(16) char VT_lds[8192];    // [64 dv][64 k] bf16, chunk-swizzled
  __shared__ __align__(16) char PT_lds[4][2048]; // per-wave [16 q][64 k] bf16, swizzled

  const int tid = threadIdx.x;
  const int wv = tid >> 6, lane = tid & 63;
  const int g16 = lane >> 4, l16 = lane & 15;
  const int l7 = l16 & 7;

  // bijective XCD swizzle: all 16 q-tiles of a (b,h) keep the same wg%8 -> same XCD
  const int wg = blockIdx.x;
  const int swz = (wg & 7) * 128 + (wg >> 3);
  const int qt = swz & 15;
  const int h = (swz >> 4) & 7;
  const int b = swz >> 7;
  const int qg = qt * 64;
  const int hb = h * HDIM;
  const size_t batch_row = (size_t)b * NSEQ;

  const int q = qg + wv * 16 + l16;              // this lane's q column

  // hoist Q as B-operand frags (col=lane&15 -> q, k=(lane>>4)*8+j -> dk),
  // pre-scaled into the exp2 domain
  short8 b_q[2];
#pragma unroll
  for (int c = 0; c < 2; ++c) {
    short8 raw = *(const short8*)(Qp + (batch_row + q) * DMODEL + hb + c * 32 + g16 * 8);
    short8 sc;
#pragma unroll
    for (int j = 0; j < 8; ++j) sc[j] = (short)f2bf(bf2f((u16)raw[j]) * SCALE_LOG2E);
    b_q[c] = sc;
  }

  float mM = -1e30f, lL = 0.f;
  f32x4 accO[4] = {};
  char* Pw = &PT_lds[wv][0];

  for (int kt = 0; kt < 16; ++kt) {
    // stage K tile via global_load_lds (linear dest + inverse-swizzled source)
#pragma unroll
    for (int r = 0; r < 2; ++r) {
      int idx = r * 256 + tid;
      int row = idx >> 3, sl = idx & 7;
      int chunk = sl ^ (row & 7);
      gload16(Kp + (batch_row + kt * 64 + row) * DMODEL + hb + chunk * 8,
              K_lds + r * 4096 + wv * 1024);
    }
    // stage V^T: coalesced 4B global loads, swizzled b128 LDS writes
    {
      int dv2 = (tid & 31) * 2;
      int kg = tid >> 5;                         // 0..7
      short8 slo, shi;
#pragma unroll
      for (int j = 0; j < 8; ++j) {
        u32 u = *(const u32*)(Vp + (batch_row + kt * 64 + kg * 8 + j) * DMODEL + hb + dv2);
        slo[j] = (short)(u & 0xffffu);
        shi[j] = (short)(u >> 16);
      }
      *(short8*)(VT_lds + dv2 * 128 + ((kg ^ (dv2 & 7)) << 4)) = slo;
      *(short8*)(VT_lds + (dv2 + 1) * 128 + ((kg ^ ((dv2 + 1) & 7)) << 4)) = shi;
    }
    __syncthreads();

    // S^T = K Q^T : A-frag row = k (kf*16 + l16), B-frag = hoisted Q
    f32x4 s_[4];
#pragma unroll
    for (int kf = 0; kf < 4; ++kf) {
      int row = kf * 16 + l16;
      short8 ak0 = *(const short8*)(K_lds + row * 128 + ((g16 ^ l7) << 4));
      short8 ak1 = *(const short8*)(K_lds + row * 128 + (((4 + g16) ^ l7) << 4));
      f32x4 acc = {0.f, 0.f, 0.f, 0.f};
      acc = __builtin_amdgcn_mfma_f32_16x16x32_bf16(ak0, b_q[0], acc, 0, 0, 0);
      acc = __builtin_amdgcn_mfma_f32_16x16x32_bf16(ak1, b_q[1], acc, 0, 0, 0);
      s_[kf] = acc;
    }

    // online softmax: lane holds S'[k][q=l16] for k = kf*16 + g16*4 + r
    u64 mks = Mb[(batch_row + q) * 16 + kt] >> (g16 * 4);
    float p[4][4];
    float mx = -1e30f;
#pragma unroll
    for (int kf = 0; kf < 4; ++kf) {
      u32 nib = ((u32)(mks >> (kf * 16))) & 15u;
#pragma unroll
      for (int r = 0; r < 4; ++r) {
        float v = ((nib >> r) & 1u) ? s_[kf][r] : -1e30f;
        p[kf][r] = v;
        mx = fmaxf(mx, v);
      }
    }
    mx = fmaxf(mx, __shfl_xor(mx, 16, 64));
    mx = fmaxf(mx, __shfl_xor(mx, 32, 64));
    float nm = fmaxf(mM, mx);
    float corr = __builtin_amdgcn_exp2f(mM - nm);
    mM = nm;
    float sum = 0.f;
#pragma unroll
    for (int kf = 0; kf < 4; ++kf)
#pragma unroll
      for (int r = 0; r < 4; ++r) {
        float e = __builtin_amdgcn_exp2f(p[kf][r] - nm);   // masked -> exp2(-inf) = 0
        p[kf][r] = e;
        sum += e;
      }
    sum += __shfl_xor(sum, 16, 64);
    sum += __shfl_xor(sum, 32, 64);
    lL = lL * corr + sum;
#pragma unroll
    for (int f = 0; f < 4; ++f) {
      accO[f][0] *= corr; accO[f][1] *= corr; accO[f][2] *= corr; accO[f][3] *= corr;
    }

    // write P^T [16 q][64 k] per-wave, 4 packed ds_write_b64 per lane
#pragma unroll
    for (int kf = 0; kf < 4; ++kf) {
      int chunk = kf * 2 + (g16 >> 1);
      int off = l16 * 128 + ((chunk ^ l7) << 4) + (g16 & 1) * 8;
      u64 pk = (u64)f2bf(p[kf][0]) | ((u64)f2bf(p[kf][1]) << 16) |
               ((u64)f2bf(p[kf][2]) << 32) | ((u64)f2bf(p[kf][3]) << 48);
      *(u64*)(Pw + off) = pk;
    }

    // PV: O^T += V^T . P^T  (A-frag from VT_lds, B-frag from wave-private P^T)
    short8 b_p[2];
#pragma unroll
    for (int kc = 0; kc < 2; ++kc)
      b_p[kc] = *(const short8*)(Pw + l16 * 128 + (((kc * 4 + g16) ^ l7) << 4));
#pragma unroll
    for (int f = 0; f < 4; ++f) {
      int vrow = f * 16 + l16;
      short8 av0 = *(const short8*)(VT_lds + vrow * 128 + ((g16 ^ l7) << 4));
      short8 av1 = *(const short8*)(VT_lds + vrow * 128 + (((4 + g16) ^ l7) << 4));
      accO[f] = __builtin_amdgcn_mfma_f32_16x16x32_bf16(av0, b_p[0], accO[f], 0, 0, 0);
      accO[f] = __builtin_amdgcn_mfma_f32_16x16x32_bf16(av1, b_p[1], accO[f], 0, 0, 0);
    }
    __syncthreads();
  }

  // epilogue: O[q][dv] = Qh[q][dv] + accO^T / l ; lane writes 4x 8B chunks
  float inv = 1.0f / fmaxf(lL, 1e-20f);
#pragma unroll
  for (int f = 0; f < 4; ++f) {
    size_t o = (batch_row + q) * DMODEL + hb + f * 16 + g16 * 4;
    u64 qh = *(const u64*)(Qp + o);
    u64 ov = 0;
#pragma unroll
    for (int r = 0; r < 4; ++r) {
      float val = accO[f][r] * inv + bf2f((u16)(qh >> (r * 16)));
      ov |= ((u64)f2bf(val)) << (r * 16);
    }
    *(u64*)(O1 + o) = ov;
  }
}

// ---------------------------------------------------------------------------
// layernorm: one wave per 512-ch row. OUTF=0 -> bf16 out, OUTF=1 -> fp32 out
// ---------------------------------------------------------------------------
template<int OUTF>
__global__ __launch_bounds__(256) void ln_kernel(
    const u16* __restrict__ X, const float* __restrict__ g, const float* __restrict__ bb,
    void* __restrict__ outv)
{
  const int tid = threadIdx.x;
  const int wv = tid >> 6, lane = tid & 63;
  const size_t row = (size_t)blockIdx.x * 4 + wv;
  short8 x8 = *(const short8*)(X + row * 512 + lane * 8);
  float xf[8];
  float s = 0.f, s2 = 0.f;
#pragma unroll
  for (int i = 0; i < 8; ++i) {
    xf[i] = bf2f((u16)x8[i]);
    s += xf[i];
    s2 += xf[i] * xf[i];
  }
#pragma unroll
  for (int d = 1; d < 64; d <<= 1) {
    s += __shfl_xor(s, d, 64);
    s2 += __shfl_xor(s2, d, 64);
  }
  float mu = s * (1.f / 512.f);
  float var = s2 * (1.f / 512.f) - mu * mu;
  float rs = rsqrtf(var + 1e-5f);
  float4 ga = *(const float4*)(g + lane * 8);
  float4 gb = *(const float4*)(g + lane * 8 + 4);
  float4 ba = *(const float4*)(bb + lane * 8);
  float4 bc = *(const float4*)(bb + lane * 8 + 4);
  float gv[8] = {ga.x, ga.y, ga.z, ga.w, gb.x, gb.y, gb.z, gb.w};
  float bv[8] = {ba.x, ba.y, ba.z, ba.w, bc.x, bc.y, bc.z, bc.w};
  float y[8];
#pragma unroll
  for (int i = 0; i < 8; ++i) y[i] = (xf[i] - mu) * rs * gv[i] + bv[i];
  if (OUTF) {
    float* o = (float*)outv + row * 512 + lane * 8;
    float4 o1 = {y[0], y[1], y[2], y[3]};
    float4 o2 = {y[4], y[5], y[6], y[7]};
    *(float4*)o = o1;
    *(float4*)(o + 4) = o2;
  } else {
    short8 o;
#pragma unroll
    for (int i = 0; i < 8; ++i) o[i] = (short)f2bf(y[i]);
    *(short8*)((u16*)outv + row * 512 + lane * 8) = o;
  }
}

// ---------------------------------------------------------------------------
extern "C" void kernel_launch(void* const* d_in, const int* in_sizes, int n_in,
                              void* d_out, int out_size, void* d_ws, size_t ws_size,
                              hipStream_t stream) {
  (void)in_sizes; (void)n_in; (void)out_size; (void)ws_size;
  const float* Q  = (const float*)d_in[0];
  const float* K  = (const float*)d_in[1];
  const float* Wq = (const float*)d_in[2];
  const float* bq = (const float*)d_in[3];
  const float* Wk = (const float*)d_in[4];
  const float* bk = (const float*)d_in[5];
  const float* Wv = (const float*)d_in[6];
  const float* bv = (const float*)d_in[7];
  const float* Wo = (const float*)d_in[8];
  const float* bo = (const float*)d_in[9];
  const float* g0 = (const float*)d_in[10];
  const float* b0 = (const float*)d_in[11];
  const float* g1 = (const float*)d_in[12];
  const float* b1 = (const float*)d_in[13];
  const int*   M  = (const int*)d_in[14];
  float* out = (float*)d_out;
  char* ws = (char*)d_ws;

  u16* Qbf = (u16*)(ws + O_QBF);
  u16* Kbf = (u16*)(ws + O_KBF);
  u16* Wb  = (u16*)(ws + O_WB);
  u64* Mb  = (u64*)(ws + O_MB);
  u16* Qp  = (u16*)(ws + O_QP);
  u16* Kp  = (u16*)(ws + O_KP);
  u16* Vp  = (u16*)(ws + O_VP);
  u16* O1  = Kbf;   // Kbf dead after gemm1
  u16* Xn  = Qp;    // Qp dead after attn
  u16* Z   = Qbf;   // Qbf dead after gemm1

  prep_kernel<<<5376, 256, 0, stream>>>(Q, K, Wq, Wk, Wv, Wo, M, Qbf, Kbf, Wb, Mb);
  gemm_bt<0><<<dim3(64, 4, 3), 256, 0, stream>>>(Qbf, Kbf, Wb, bq, bk, bv, Qp, nullptr);
  attn_kernel<<<1024, 256, 0, stream>>>(Qp, Kp, Vp, Mb, O1);
  ln_kernel<0><<<2048, 256, 0, stream>>>(O1, g0, b0, (void*)Xn);
  gemm_bt<1><<<dim3(64, 4, 1), 256, 0, stream>>>(Xn, nullptr, Wb + 3 * 262144, bo,
                                                 nullptr, nullptr, Z, Xn);
  ln_kernel<1><<<2048, 256, 0, stream>>>(Z, g1, b1, (void*)out);
}

// Round 4
// 117.960 us; speedup vs baseline: 1.2304x; 1.0104x over previous
//
#include <hip/hip_runtime.h>

typedef unsigned short u16;
typedef unsigned int u32;
typedef unsigned long long u64;
typedef __attribute__((ext_vector_type(8))) short short8;
typedef __attribute__((ext_vector_type(4))) float f32x4;
typedef __attribute__((ext_vector_type(4))) u32 u32x4;

#define BATCH 8
#define NSEQ 1024
#define DMODEL 512
#define HDIM 64
// QK_SCALE * log2(e): softmax computed in exp2 domain
#define SCALE_LOG2E 0.06375871114929199f

// workspace byte offsets
#define O_QBF 0ULL
#define O_KBF 8388608ULL
#define O_WB  16777216ULL
#define O_QP  19922944ULL
#define O_KP  28311552ULL
#define O_VP  36700160ULL

__device__ __forceinline__ u16 f2bf(float f) {
  u32 u = __float_as_uint(f);
  u = (u + 0x7fffu + ((u >> 16) & 1u)) >> 16;
  return (u16)u;
}
__device__ __forceinline__ float bf2f(u16 s) {
  return __uint_as_float(((u32)s) << 16);
}
__device__ __forceinline__ void gload16(const void* g, void* l) {
  __builtin_amdgcn_global_load_lds((const __attribute__((address_space(1))) void*)g,
                                   (__attribute__((address_space(3))) void*)l, 16, 0, 0);
}
// pack two f32 -> u32 of 2 bf16 (lo = a, hi = b)
__device__ __forceinline__ u32 cvtpk(float a, float b) {
  u32 r;
  asm("v_cvt_pk_bf16_f32 %0, %1, %2" : "=v"(r) : "v"(a), "v"(b));
  return r;
}

// ---------------------------------------------------------------------------
// prep: fp32->bf16 Q/K, transpose-convert weights to [N][K],
//       M -> bf16 additive bias {0, -32768} stored in d_out (dead until ln1)
// ---------------------------------------------------------------------------
__global__ __launch_bounds__(256) void prep_kernel(
    const float* __restrict__ Q, const float* __restrict__ K,
    const float* __restrict__ Wq, const float* __restrict__ Wk,
    const float* __restrict__ Wv, const float* __restrict__ Wo,
    const int* __restrict__ M,
    u16* __restrict__ Qbf, u16* __restrict__ Kbf, u16* __restrict__ Wb,
    u16* __restrict__ Mbias)
{
  __shared__ float lds[64 * 68];
  const int bi = blockIdx.x, t = threadIdx.x;
  if (bi < 4096) {
    const float* src = (bi < 2048) ? Q : K;
    u16* dst = (bi < 2048) ? Qbf : Kbf;
    const int lb = bi & 2047;
    const size_t base = ((size_t)lb * 256 + t) * 8;
    float4 a = *(const float4*)(src + base);
    float4 c = *(const float4*)(src + base + 4);
    short8 o;
    o[0] = (short)f2bf(a.x); o[1] = (short)f2bf(a.y);
    o[2] = (short)f2bf(a.z); o[3] = (short)f2bf(a.w);
    o[4] = (short)f2bf(c.x); o[5] = (short)f2bf(c.y);
    o[6] = (short)f2bf(c.z); o[7] = (short)f2bf(c.w);
    *(short8*)(dst + base) = o;
  } else if (bi < 4352) {
    const int qid = bi - 4096;
    const int w = qid >> 6;
    const int tt = qid & 63;
    const int tr = tt >> 3, tc = tt & 7;          // 64x64 tile at (tr*64 k, tc*64 n)
    const float* W = (w == 0) ? Wq : (w == 1) ? Wk : (w == 2) ? Wv : Wo;
#pragma unroll
    for (int j = 0; j < 4; ++j) {
      int vi = j * 256 + t;
      int row = vi >> 4, c4 = vi & 15;
      float4 v = *(const float4*)(W + (size_t)(tr * 64 + row) * 512 + tc * 64 + c4 * 4);
      lds[row * 68 + c4 * 4 + 0] = v.x;
      lds[row * 68 + c4 * 4 + 1] = v.y;
      lds[row * 68 + c4 * 4 + 2] = v.z;
      lds[row * 68 + c4 * 4 + 3] = v.w;
    }
    __syncthreads();
    // 64 n-rows x 8 k8-chunks = 512 short8 stores -> exactly 2 iterations
#pragma unroll
    for (int j = 0; j < 2; ++j) {
      int oi = j * 256 + t;
      int nl = oi >> 3, k8 = oi & 7;
      short8 o;
#pragma unroll
      for (int i = 0; i < 8; ++i) o[i] = (short)f2bf(lds[(k8 * 8 + i) * 68 + nl]);
      *(short8*)(Wb + (size_t)w * 262144 + (size_t)(tc * 64 + nl) * 512 + tr * 64 + k8 * 8) = o;
    }
  } else {
    // mask -> bf16 additive bias: keep -> 0.0, masked -> -32768.0 (0xC700)
    const int pb = bi - 4352;                     // 2048 blocks
    const size_t idx = ((size_t)pb * 256 + t) * 16;
    const int4* Ms = (const int4*)(M + idx);
    int4 m0 = Ms[0], m1 = Ms[1], m2 = Ms[2], m3 = Ms[3];
    int mv[16] = {m0.x, m0.y, m0.z, m0.w, m1.x, m1.y, m1.z, m1.w,
                  m2.x, m2.y, m2.z, m2.w, m3.x, m3.y, m3.z, m3.w};
    short8 o0, o1;
#pragma unroll
    for (int i = 0; i < 8; ++i) {
      o0[i] = mv[i] ? (short)0 : (short)0xC700;
      o1[i] = mv[8 + i] ? (short)0 : (short)0xC700;
    }
    *(short8*)(Mbias + idx) = o0;
    *(short8*)(Mbias + idx + 8) = o1;
  }
}

// ---------------------------------------------------------------------------
// gemm_bt: C[M=8192,N=512] = A[M,512] * Wb^T (Wb stored [N][K]) + bias
// ---------------------------------------------------------------------------
template<int MODE>
__global__ __launch_bounds__(256) void gemm_bt(
    const u16* __restrict__ Aq, const u16* __restrict__ Ak,
    const u16* __restrict__ Wb,
    const float* __restrict__ b0, const float* __restrict__ b1, const float* __restrict__ b2,
    u16* __restrict__ outp, const u16* __restrict__ resid)
{
  __shared__ __align__(16) char Alds[8192];
  __shared__ __align__(16) char Blds[8192];
  const int tid = threadIdx.x;
  const int wv = tid >> 6, lane = tid & 63;
  const int g16 = lane >> 4, l16 = lane & 15;
  const int wr = wv >> 1, wc = wv & 1;
  const int bx = blockIdx.x, by = blockIdx.y, bz = blockIdx.z;

  const u16* A; const u16* W; const float* bias; u16* out;
  if (MODE == 0) {
    A = (bz == 0) ? Aq : Ak;
    W = Wb + (size_t)bz * 262144;
    bias = (bz == 0) ? b0 : ((bz == 1) ? b1 : b2);
    out = outp + (size_t)bz * 4194304;
  } else {
    A = Aq; W = Wb; bias = b0; out = outp;
  }

  const int m0 = bx * 128, n0 = by * 128;
  f32x4 acc[4][4] = {};

  for (int kt = 0; kt < 16; ++kt) {
    const int k0 = kt * 32;
#pragma unroll
    for (int r = 0; r < 2; ++r) {
      int idx = r * 256 + tid;
      int row = idx >> 2, sl = idx & 3;
      gload16(A + (size_t)(m0 + row) * 512 + k0 + sl * 8, Alds + r * 4096 + wv * 1024);
      gload16(W + (size_t)(n0 + row) * 512 + k0 + sl * 8, Blds + r * 4096 + wv * 1024);
    }
    __syncthreads();
    short8 af[4], bfr[4];
#pragma unroll
    for (int mt = 0; mt < 4; ++mt)
      af[mt] = *(const short8*)(Alds + (wr * 64 + mt * 16 + l16) * 64 + g16 * 16);
#pragma unroll
    for (int nt = 0; nt < 4; ++nt)
      bfr[nt] = *(const short8*)(Blds + (wc * 64 + nt * 16 + l16) * 64 + g16 * 16);
#pragma unroll
    for (int mt = 0; mt < 4; ++mt)
#pragma unroll
      for (int nt = 0; nt < 4; ++nt)
        acc[mt][nt] = __builtin_amdgcn_mfma_f32_16x16x32_bf16(af[mt], bfr[nt], acc[mt][nt], 0, 0, 0);
    __syncthreads();
  }

#pragma unroll
  for (int nt = 0; nt < 4; ++nt) {
    int col = n0 + wc * 64 + nt * 16 + l16;
    float bcol = bias[col];
#pragma unroll
    for (int mt = 0; mt < 4; ++mt) {
#pragma unroll
      for (int r = 0; r < 4; ++r) {
        int row = m0 + wr * 64 + mt * 16 + g16 * 4 + r;
        float v = acc[mt][nt][r] + bcol;
        if (MODE == 1) {
          v = fmaxf(v, 0.f) + bf2f(resid[(size_t)row * 512 + col]);
        }
        out[(size_t)row * 512 + col] = f2bf(v);
      }
    }
  }
}

// ---------------------------------------------------------------------------
// flash attention, swapped-operand + 2-phase pipeline.
//   S^T[k][q] = mfma(A=K, B=Q) + bias(C-in)  -> lane owns q=lane&15, k local
//   O^T[dv][q] = mfma(A=V^T, B=P^T)
// Double-buffered K/V LDS, ONE barrier per tile, loads issued a tile early.
// ---------------------------------------------------------------------------
__global__ __launch_bounds__(256, 4) void attn_kernel(
    const u16* __restrict__ Qp, const u16* __restrict__ Kp, const u16* __restrict__ Vp,
    const u16* __restrict__ Mbias, u16* __restrict__ O1)
{
  __shared__ __align__(16) char K_lds[2][8192];   // [64 k][64 dk] bf16, chunk-swizzled
  __shared__ __align__(16) char VT_lds[2][8192];  // [64 dv][64 k] bf16, chunk-swizzled
  __shared__ __align__(16) char PT_lds[4][2048];  // per-wave [16 q][64 k] bf16, swizzled

  const int tid = threadIdx.x;
  const int wv = tid >> 6, lane = tid & 63;
  const int g16 = lane >> 4, l16 = lane & 15;
  const int l7 = l16 & 7;

  // bijective XCD swizzle: all 16 q-tiles of a (b,h) share one XCD's L2
  const int wg = blockIdx.x;
  const int swz = (wg & 7) * 128 + (wg >> 3);
  const int qt = swz & 15;
  const int h = (swz >> 4) & 7;
  const int b = swz >> 7;
  const int qg = qt * 64;
  const int hb = h * HDIM;
  const size_t batch_row = (size_t)b * NSEQ;

  const int q = qg + wv * 16 + l16;               // this lane's q column
  const int dv2 = (tid & 31) * 2;                 // V staging lanes
  const int kg = tid >> 5;

  // hoist Q as B-operand frags, pre-scaled into the exp2 domain
  short8 b_q[2];
#pragma unroll
  for (int c = 0; c < 2; ++c) {
    short8 raw = *(const short8*)(Qp + (batch_row + q) * DMODEL + hb + c * 32 + g16 * 8);
    short8 sc;
#pragma unroll
    for (int j = 0; j < 8; ++j) sc[j] = (short)f2bf(bf2f((u16)raw[j]) * SCALE_LOG2E);
    b_q[c] = sc;
  }

  const u64* Mq = (const u64*)(Mbias + (batch_row + q) * 1024);

  auto stageK = [&](int kt2, char* dst) {
#pragma unroll
    for (int r = 0; r < 2; ++r) {
      int idx = r * 256 + tid;
      int row = idx >> 3, sl = idx & 7;
      int chunk = sl ^ (row & 7);
      gload16(Kp + (batch_row + kt2 * 64 + row) * DMODEL + hb + chunk * 8,
              dst + r * 4096 + wv * 1024);
    }
  };
  auto loadV = [&](int kt2, u32* vr) {
#pragma unroll
    for (int j = 0; j < 8; ++j)
      vr[j] = *(const u32*)(Vp + (batch_row + kt2 * 64 + kg * 8 + j) * DMODEL + hb + dv2);
  };
  auto writeVT = [&](const u32* vr, char* dstv) {
    u32x4 lo, hi;
#pragma unroll
    for (int i = 0; i < 4; ++i) {
      lo[i] = __builtin_amdgcn_perm(vr[2 * i + 1], vr[2 * i], 0x05040100u);
      hi[i] = __builtin_amdgcn_perm(vr[2 * i + 1], vr[2 * i], 0x07060302u);
    }
    *(u32x4*)(dstv + dv2 * 128 + ((kg ^ (dv2 & 7)) << 4)) = lo;
    *(u32x4*)(dstv + (dv2 + 1) * 128 + ((kg ^ ((dv2 + 1) & 7)) << 4)) = hi;
  };
  auto loadBias = [&](int kt2, u64* bb) {
#pragma unroll
    for (int kf = 0; kf < 4; ++kf) bb[kf] = Mq[kt2 * 16 + kf * 4 + g16];
  };

  float mM = -1e30f, lL = 0.f;
  f32x4 accO[4] = {};
  char* Pw = &PT_lds[wv][0];

  // prologue: stage tile 0, prefetch V(1)
  u32 vreg[8];
  u64 bias_cur[4], bias_next[4];
  stageK(0, &K_lds[0][0]);
  loadV(0, vreg);
  loadBias(0, bias_cur);
  writeVT(vreg, &VT_lds[0][0]);
  loadV(1, vreg);

  for (int kt = 0; kt < 16; ++kt) {
    __syncthreads();   // staged(kt) visible; buffers (kt+1)&1 free
    char* Kc = &K_lds[kt & 1][0];
    char* Vc = &VT_lds[kt & 1][0];
    if (kt < 15) {
      writeVT(vreg, &VT_lds[(kt + 1) & 1][0]);    // V(kt+1) regs -> LDS
      stageK(kt + 1, &K_lds[(kt + 1) & 1][0]);    // K(kt+1) async
      loadBias(kt + 1, bias_next);
    }
    if (kt < 14) loadV(kt + 2, vreg);

    // ---- compute tile kt ----
    // unpack bias fragment (C-in): k = kf*16 + g16*4 + r
    f32x4 s_[4];
#pragma unroll
    for (int kf = 0; kf < 4; ++kf) {
      u32 blo = (u32)bias_cur[kf];
      u32 bhi = (u32)(bias_cur[kf] >> 32);
      f32x4 acc;
      acc[0] = __uint_as_float(blo << 16);
      acc[1] = __uint_as_float(blo & 0xffff0000u);
      acc[2] = __uint_as_float(bhi << 16);
      acc[3] = __uint_as_float(bhi & 0xffff0000u);
      int row = kf * 16 + l16;
      short8 ak0 = *(const short8*)(Kc + row * 128 + ((g16 ^ l7) << 4));
      short8 ak1 = *(const short8*)(Kc + row * 128 + (((4 + g16) ^ l7) << 4));
      acc = __builtin_amdgcn_mfma_f32_16x16x32_bf16(ak0, b_q[0], acc, 0, 0, 0);
      acc = __builtin_amdgcn_mfma_f32_16x16x32_bf16(ak1, b_q[1], acc, 0, 0, 0);
      s_[kf] = acc;
    }

    // online softmax in exp2 domain (masked entries sit at ~-32768)
    float mx = -1e30f;
#pragma unroll
    for (int kf = 0; kf < 4; ++kf)
#pragma unroll
      for (int r = 0; r < 4; ++r) mx = fmaxf(mx, s_[kf][r]);
    mx = fmaxf(mx, __shfl_xor(mx, 16, 64));
    mx = fmaxf(mx, __shfl_xor(mx, 32, 64));

    // defer-max: skip rescale when no lane's max grew past mM + 8
    if (!__all(mx <= mM + 8.0f)) {
      float nm = fmaxf(mM, mx);
      float corr = __builtin_amdgcn_exp2f(mM - nm);
      mM = nm;
      lL *= corr;
#pragma unroll
      for (int f = 0; f < 4; ++f) accO[f] *= corr;
    }

    float sum = 0.f;
    float p[4][4];
#pragma unroll
    for (int kf = 0; kf < 4; ++kf)
#pragma unroll
      for (int r = 0; r < 4; ++r) {
        float e = __builtin_amdgcn_exp2f(s_[kf][r] - mM);
        p[kf][r] = e;
        sum += e;
      }
    sum += __shfl_xor(sum, 16, 64);
    sum += __shfl_xor(sum, 32, 64);
    lL += sum;

    // write P^T [16 q][64 k] per-wave: 2 cvt_pk + 1 ds_write_b64 per kf
#pragma unroll
    for (int kf = 0; kf < 4; ++kf) {
      int chunk = kf * 2 + (g16 >> 1);
      int off = l16 * 128 + ((chunk ^ l7) << 4) + (g16 & 1) * 8;
      u32 c0 = cvtpk(p[kf][0], p[kf][1]);
      u32 c1 = cvtpk(p[kf][2], p[kf][3]);
      *(u64*)(Pw + off) = (u64)c0 | ((u64)c1 << 32);
    }

    // PV: O^T += V^T . P^T
    short8 b_p[2];
#pragma unroll
    for (int kc = 0; kc < 2; ++kc)
      b_p[kc] = *(const short8*)(Pw + l16 * 128 + (((kc * 4 + g16) ^ l7) << 4));
#pragma unroll
    for (int f = 0; f < 4; ++f) {
      int vrow = f * 16 + l16;
      short8 av0 = *(const short8*)(Vc + vrow * 128 + ((g16 ^ l7) << 4));
      short8 av1 = *(const short8*)(Vc + vrow * 128 + (((4 + g16) ^ l7) << 4));
      accO[f] = __builtin_amdgcn_mfma_f32_16x16x32_bf16(av0, b_p[0], accO[f], 0, 0, 0);
      accO[f] = __builtin_amdgcn_mfma_f32_16x16x32_bf16(av1, b_p[1], accO[f], 0, 0, 0);
    }

    if (kt < 15) {
#pragma unroll
      for (int kf = 0; kf < 4; ++kf) bias_cur[kf] = bias_next[kf];
    }
  }

  // epilogue: O[q][dv] = Qh[q][dv] + accO^T / l
  float inv = 1.0f / fmaxf(lL, 1e-20f);
#pragma unroll
  for (int f = 0; f < 4; ++f) {
    size_t o = (batch_row + q) * DMODEL + hb + f * 16 + g16 * 4;
    u64 qh = *(const u64*)(Qp + o);
    u64 ov = 0;
#pragma unroll
    for (int r = 0; r < 4; ++r) {
      float val = accO[f][r] * inv + bf2f((u16)(qh >> (r * 16)));
      ov |= ((u64)f2bf(val)) << (r * 16);
    }
    *(u64*)(O1 + o) = ov;
  }
}

// ---------------------------------------------------------------------------
// layernorm: one wave per 512-ch row. OUTF=0 -> bf16 out, OUTF=1 -> fp32 out
// ---------------------------------------------------------------------------
template<int OUTF>
__global__ __launch_bounds__(256) void ln_kernel(
    const u16* __restrict__ X, const float* __restrict__ g, const float* __restrict__ bb,
    void* __restrict__ outv)
{
  const int tid = threadIdx.x;
  const int wv = tid >> 6, lane = tid & 63;
  const size_t row = (size_t)blockIdx.x * 4 + wv;
  short8 x8 = *(const short8*)(X + row * 512 + lane * 8);
  float xf[8];
  float s = 0.f, s2 = 0.f;
#pragma unroll
  for (int i = 0; i < 8; ++i) {
    xf[i] = bf2f((u16)x8[i]);
    s += xf[i];
    s2 += xf[i] * xf[i];
  }
#pragma unroll
  for (int d = 1; d < 64; d <<= 1) {
    s += __shfl_xor(s, d, 64);
    s2 += __shfl_xor(s2, d, 64);
  }
  float mu = s * (1.f / 512.f);
  float var = s2 * (1.f / 512.f) - mu * mu;
  float rs = rsqrtf(var + 1e-5f);
  float4 ga = *(const float4*)(g + lane * 8);
  float4 gb = *(const float4*)(g + lane * 8 + 4);
  float4 ba = *(const float4*)(bb + lane * 8);
  float4 bc = *(const float4*)(bb + lane * 8 + 4);
  float gv[8] = {ga.x, ga.y, ga.z, ga.w, gb.x, gb.y, gb.z, gb.w};
  float bv[8] = {ba.x, ba.y, ba.z, ba.w, bc.x, bc.y, bc.z, bc.w};
  float y[8];
#pragma unroll
  for (int i = 0; i < 8; ++i) y[i] = (xf[i] - mu) * rs * gv[i] + bv[i];
  if (OUTF) {
    float* o = (float*)outv + row * 512 + lane * 8;
    float4 o1 = {y[0], y[1], y[2], y[3]};
    float4 o2 = {y[4], y[5], y[6], y[7]};
    *(float4*)o = o1;
    *(float4*)(o + 4) = o2;
  } else {
    short8 o;
#pragma unroll
    for (int i = 0; i < 8; ++i) o[i] = (short)f2bf(y[i]);
    *(short8*)((u16*)outv + row * 512 + lane * 8) = o;
  }
}

// ---------------------------------------------------------------------------
extern "C" void kernel_launch(void* const* d_in, const int* in_sizes, int n_in,
                              void* d_out, int out_size, void* d_ws, size_t ws_size,
                              hipStream_t stream) {
  (void)in_sizes; (void)n_in; (void)out_size; (void)ws_size;
  const float* Q  = (const float*)d_in[0];
  const float* K  = (const float*)d_in[1];
  const float* Wq = (const float*)d_in[2];
  const float* bq = (const float*)d_in[3];
  const float* Wk = (const float*)d_in[4];
  const float* bk = (const float*)d_in[5];
  const float* Wv = (const float*)d_in[6];
  const float* bv = (const float*)d_in[7];
  const float* Wo = (const float*)d_in[8];
  const float* bo = (const float*)d_in[9];
  const float* g0 = (const float*)d_in[10];
  const float* b0 = (const float*)d_in[11];
  const float* g1 = (const float*)d_in[12];
  const float* b1 = (const float*)d_in[13];
  const int*   M  = (const int*)d_in[14];
  float* out = (float*)d_out;
  char* ws = (char*)d_ws;

  u16* Qbf = (u16*)(ws + O_QBF);
  u16* Kbf = (u16*)(ws + O_KBF);
  u16* Wb  = (u16*)(ws + O_WB);
  u16* Qp  = (u16*)(ws + O_QP);
  u16* Kp  = (u16*)(ws + O_KP);
  u16* Vp  = (u16*)(ws + O_VP);
  u16* Mbias = (u16*)d_out;  // 16.77 MB, exactly out-size; dead until ln1
  u16* O1  = Kbf;   // Kbf dead after gemm1
  u16* Xn  = Qp;    // Qp dead after attn
  u16* Z   = Qbf;   // Qbf dead after gemm1

  prep_kernel<<<6400, 256, 0, stream>>>(Q, K, Wq, Wk, Wv, Wo, M, Qbf, Kbf, Wb, Mbias);
  gemm_bt<0><<<dim3(64, 4, 3), 256, 0, stream>>>(Qbf, Kbf, Wb, bq, bk, bv, Qp, nullptr);
  attn_kernel<<<1024, 256, 0, stream>>>(Qp, Kp, Vp, Mbias, O1);
  ln_kernel<0><<<2048, 256, 0, stream>>>(O1, g0, b0, (void*)Xn);
  gemm_bt<1><<<dim3(64, 4, 1), 256, 0, stream>>>(Xn, nullptr, Wb + 3 * 262144, bo,
                                                 nullptr, nullptr, Z, Xn);
  ln_kernel<1><<<2048, 256, 0, stream>>>(Z, g1, b1, (void*)out);
}

// Round 5
// 113.103 us; speedup vs baseline: 1.2833x; 1.0429x over previous
//
#include <hip/hip_runtime.h>

typedef unsigned short u16;
typedef unsigned int u32;
typedef unsigned long long u64;
typedef __attribute__((ext_vector_type(8))) short short8;
typedef __attribute__((ext_vector_type(4))) float f32x4;
typedef __attribute__((ext_vector_type(4))) u32 u32x4;

#define BATCH 8
#define NSEQ 1024
#define DMODEL 512
#define HDIM 64
// QK_SCALE * log2(e): softmax computed in exp2 domain
#define SCALE_LOG2E 0.06375871114929199f
#define FIXED_MAX 16.0f

// workspace byte offsets
#define O_QBF 0ULL
#define O_KBF 8388608ULL
#define O_WB  16777216ULL
#define O_QP  19922944ULL
#define O_KP  28311552ULL
#define O_VP  36700160ULL

__device__ __forceinline__ u16 f2bf(float f) {
  u32 u = __float_as_uint(f);
  u = (u + 0x7fffu + ((u >> 16) & 1u)) >> 16;
  return (u16)u;
}
__device__ __forceinline__ float bf2f(u16 s) {
  return __uint_as_float(((u32)s) << 16);
}
__device__ __forceinline__ void gload16(const void* g, void* l) {
  __builtin_amdgcn_global_load_lds((const __attribute__((address_space(1))) void*)g,
                                   (__attribute__((address_space(3))) void*)l, 16, 0, 0);
}
// pack two f32 -> u32 of 2 bf16 (lo = a, hi = b)
__device__ __forceinline__ u32 cvtpk(float a, float b) {
  u32 r;
  asm("v_cvt_pk_bf16_f32 %0, %1, %2" : "=v"(r) : "v"(a), "v"(b));
  return r;
}

// ---------------------------------------------------------------------------
// prep: fp32->bf16 Q/K, transpose-convert weights to [N][K],
//       M -> bf16 additive bias {0, -32768} stored in d_out (dead until ln1)
// ---------------------------------------------------------------------------
__global__ __launch_bounds__(256) void prep_kernel(
    const float* __restrict__ Q, const float* __restrict__ K,
    const float* __restrict__ Wq, const float* __restrict__ Wk,
    const float* __restrict__ Wv, const float* __restrict__ Wo,
    const int* __restrict__ M,
    u16* __restrict__ Qbf, u16* __restrict__ Kbf, u16* __restrict__ Wb,
    u16* __restrict__ Mbias)
{
  __shared__ float lds[64 * 68];
  const int bi = blockIdx.x, t = threadIdx.x;
  if (bi < 4096) {
    const float* src = (bi < 2048) ? Q : K;
    u16* dst = (bi < 2048) ? Qbf : Kbf;
    const int lb = bi & 2047;
    const size_t base = ((size_t)lb * 256 + t) * 8;
    float4 a = *(const float4*)(src + base);
    float4 c = *(const float4*)(src + base + 4);
    short8 o;
    o[0] = (short)f2bf(a.x); o[1] = (short)f2bf(a.y);
    o[2] = (short)f2bf(a.z); o[3] = (short)f2bf(a.w);
    o[4] = (short)f2bf(c.x); o[5] = (short)f2bf(c.y);
    o[6] = (short)f2bf(c.z); o[7] = (short)f2bf(c.w);
    *(short8*)(dst + base) = o;
  } else if (bi < 4352) {
    const int qid = bi - 4096;
    const int w = qid >> 6;
    const int tt = qid & 63;
    const int tr = tt >> 3, tc = tt & 7;          // 64x64 tile at (tr*64 k, tc*64 n)
    const float* W = (w == 0) ? Wq : (w == 1) ? Wk : (w == 2) ? Wv : Wo;
#pragma unroll
    for (int j = 0; j < 4; ++j) {
      int vi = j * 256 + t;
      int row = vi >> 4, c4 = vi & 15;
      float4 v = *(const float4*)(W + (size_t)(tr * 64 + row) * 512 + tc * 64 + c4 * 4);
      lds[row * 68 + c4 * 4 + 0] = v.x;
      lds[row * 68 + c4 * 4 + 1] = v.y;
      lds[row * 68 + c4 * 4 + 2] = v.z;
      lds[row * 68 + c4 * 4 + 3] = v.w;
    }
    __syncthreads();
    // 64 n-rows x 8 k8-chunks = 512 short8 stores -> exactly 2 iterations
#pragma unroll
    for (int j = 0; j < 2; ++j) {
      int oi = j * 256 + t;
      int nl = oi >> 3, k8 = oi & 7;
      short8 o;
#pragma unroll
      for (int i = 0; i < 8; ++i) o[i] = (short)f2bf(lds[(k8 * 8 + i) * 68 + nl]);
      *(short8*)(Wb + (size_t)w * 262144 + (size_t)(tc * 64 + nl) * 512 + tr * 64 + k8 * 8) = o;
    }
  } else {
    // mask -> bf16 additive bias: keep -> 0.0, masked -> -32768.0 (0xC700)
    const int pb = bi - 4352;                     // 2048 blocks
    const size_t idx = ((size_t)pb * 256 + t) * 16;
    const int4* Ms = (const int4*)(M + idx);
    int4 m0 = Ms[0], m1 = Ms[1], m2 = Ms[2], m3 = Ms[3];
    int mv[16] = {m0.x, m0.y, m0.z, m0.w, m1.x, m1.y, m1.z, m1.w,
                  m2.x, m2.y, m2.z, m2.w, m3.x, m3.y, m3.z, m3.w};
    short8 o0, o1;
#pragma unroll
    for (int i = 0; i < 8; ++i) {
      o0[i] = mv[i] ? (short)0 : (short)0xC700;
      o1[i] = mv[8 + i] ? (short)0 : (short)0xC700;
    }
    *(short8*)(Mbias + idx) = o0;
    *(short8*)(Mbias + idx + 8) = o1;
  }
}

// ---------------------------------------------------------------------------
// gemm_bt: C[M=8192,N=512] = A[M,512] * Wb^T (Wb stored [N][K]) + bias
// ---------------------------------------------------------------------------
template<int MODE>
__global__ __launch_bounds__(256) void gemm_bt(
    const u16* __restrict__ Aq, const u16* __restrict__ Ak,
    const u16* __restrict__ Wb,
    const float* __restrict__ b0, const float* __restrict__ b1, const float* __restrict__ b2,
    u16* __restrict__ outp, const u16* __restrict__ resid)
{
  __shared__ __align__(16) char Alds[8192];
  __shared__ __align__(16) char Blds[8192];
  const int tid = threadIdx.x;
  const int wv = tid >> 6, lane = tid & 63;
  const int g16 = lane >> 4, l16 = lane & 15;
  const int wr = wv >> 1, wc = wv & 1;
  const int bx = blockIdx.x, by = blockIdx.y, bz = blockIdx.z;

  const u16* A; const u16* W; const float* bias; u16* out;
  if (MODE == 0) {
    A = (bz == 0) ? Aq : Ak;
    W = Wb + (size_t)bz * 262144;
    bias = (bz == 0) ? b0 : ((bz == 1) ? b1 : b2);
    out = outp + (size_t)bz * 4194304;
  } else {
    A = Aq; W = Wb; bias = b0; out = outp;
  }

  const int m0 = bx * 128, n0 = by * 128;
  f32x4 acc[4][4] = {};

  for (int kt = 0; kt < 16; ++kt) {
    const int k0 = kt * 32;
#pragma unroll
    for (int r = 0; r < 2; ++r) {
      int idx = r * 256 + tid;
      int row = idx >> 2, sl = idx & 3;
      gload16(A + (size_t)(m0 + row) * 512 + k0 + sl * 8, Alds + r * 4096 + wv * 1024);
      gload16(W + (size_t)(n0 + row) * 512 + k0 + sl * 8, Blds + r * 4096 + wv * 1024);
    }
    __syncthreads();
    short8 af[4], bfr[4];
#pragma unroll
    for (int mt = 0; mt < 4; ++mt)
      af[mt] = *(const short8*)(Alds + (wr * 64 + mt * 16 + l16) * 64 + g16 * 16);
#pragma unroll
    for (int nt = 0; nt < 4; ++nt)
      bfr[nt] = *(const short8*)(Blds + (wc * 64 + nt * 16 + l16) * 64 + g16 * 16);
#pragma unroll
    for (int mt = 0; mt < 4; ++mt)
#pragma unroll
      for (int nt = 0; nt < 4; ++nt)
        acc[mt][nt] = __builtin_amdgcn_mfma_f32_16x16x32_bf16(af[mt], bfr[nt], acc[mt][nt], 0, 0, 0);
    __syncthreads();
  }

#pragma unroll
  for (int nt = 0; nt < 4; ++nt) {
    int col = n0 + wc * 64 + nt * 16 + l16;
    float bcol = bias[col];
#pragma unroll
    for (int mt = 0; mt < 4; ++mt) {
#pragma unroll
      for (int r = 0; r < 4; ++r) {
        int row = m0 + wr * 64 + mt * 16 + g16 * 4 + r;
        float v = acc[mt][nt][r] + bcol;
        if (MODE == 1) {
          v = fmaxf(v, 0.f) + bf2f(resid[(size_t)row * 512 + col]);
        }
        out[(size_t)row * 512 + col] = f2bf(v);
      }
    }
  }
}

// ---------------------------------------------------------------------------
// flash attention, swapped-operand, STATIC-MAX softmax, q=32 per wave.
//   S^T[k][q] = mfma(A=K, B=Q) + bias(C-in); p = exp2(S' - 16) (no max track)
//   O^T[dv][q] = mfma(A=V^T, B=P^T); l reduced once at the end.
// Block = 128 q (4 waves x 32), KBLK=64, double-buffered K/V, 1 barrier/tile.
// ---------------------------------------------------------------------------
__global__ __launch_bounds__(256, 2) void attn_kernel(
    const u16* __restrict__ Qp, const u16* __restrict__ Kp, const u16* __restrict__ Vp,
    const u16* __restrict__ Mbias, u16* __restrict__ O1)
{
  __shared__ __align__(16) char K_lds[2][8192];    // [64 k][64 dk] bf16, chunk-swizzled
  __shared__ __align__(16) char VT_lds[2][8192];   // [64 dv][64 k] bf16, chunk-swizzled
  __shared__ __align__(16) char PT_lds[4][2][2048];// per-wave per-m [16 q][64 k] bf16

  const int tid = threadIdx.x;
  const int wv = tid >> 6, lane = tid & 63;
  const int g16 = lane >> 4, l16 = lane & 15;
  const int l7 = l16 & 7;

  // XCD swizzle keyed on batch: all 64 (h,qt) blocks of batch b -> XCD b.
  // K/V slices (2 MB) stay L2-resident; h-blocks with equal qt share bias.
  const int wg = blockIdx.x;                       // 512 blocks
  const int swz = (wg & 7) * 64 + (wg >> 3);
  const int qt = swz & 7;
  const int h = (swz >> 3) & 7;
  const int b = swz >> 6;
  const int qg = qt * 128;
  const int hb = h * HDIM;
  const size_t batch_row = (size_t)b * NSEQ;

  const int qbase = qg + wv * 32;
  const int dv2 = (tid & 31) * 2;                  // V staging lanes
  const int kg = tid >> 5;

  // hoist Q as B-operand frags for both m, pre-scaled into the exp2 domain
  short8 b_q[2][2];
#pragma unroll
  for (int m = 0; m < 2; ++m)
#pragma unroll
    for (int c = 0; c < 2; ++c) {
      short8 raw = *(const short8*)(Qp + (batch_row + qbase + m * 16 + l16) * DMODEL +
                                    hb + c * 32 + g16 * 8);
      short8 sc;
#pragma unroll
      for (int j = 0; j < 8; ++j) sc[j] = (short)f2bf(bf2f((u16)raw[j]) * SCALE_LOG2E);
      b_q[m][c] = sc;
    }

  const u64* Mq0 = (const u64*)(Mbias + (batch_row + qbase + l16) * 1024);
  const u64* Mq1 = (const u64*)(Mbias + (batch_row + qbase + 16 + l16) * 1024);

  auto stageK = [&](int kt2, char* dst) {
#pragma unroll
    for (int r = 0; r < 2; ++r) {
      int idx = r * 256 + tid;
      int row = idx >> 3, sl = idx & 7;
      int chunk = sl ^ (row & 7);
      gload16(Kp + (batch_row + kt2 * 64 + row) * DMODEL + hb + chunk * 8,
              dst + r * 4096 + wv * 1024);
    }
  };
  auto loadV = [&](int kt2, u32* vr) {
#pragma unroll
    for (int j = 0; j < 8; ++j)
      vr[j] = *(const u32*)(Vp + (batch_row + kt2 * 64 + kg * 8 + j) * DMODEL + hb + dv2);
  };
  auto writeVT = [&](const u32* vr, char* dstv) {
    u32x4 lo, hi;
#pragma unroll
    for (int i = 0; i < 4; ++i) {
      lo[i] = __builtin_amdgcn_perm(vr[2 * i + 1], vr[2 * i], 0x05040100u);
      hi[i] = __builtin_amdgcn_perm(vr[2 * i + 1], vr[2 * i], 0x07060302u);
    }
    *(u32x4*)(dstv + dv2 * 128 + ((kg ^ (dv2 & 7)) << 4)) = lo;
    *(u32x4*)(dstv + (dv2 + 1) * 128 + ((kg ^ ((dv2 + 1) & 7)) << 4)) = hi;
  };
  auto loadBias = [&](int kt2, u64* bb) {
#pragma unroll
    for (int kf = 0; kf < 4; ++kf) {
      bb[kf] = Mq0[kt2 * 16 + kf * 4 + g16];
      bb[4 + kf] = Mq1[kt2 * 16 + kf * 4 + g16];
    }
  };

  float lL[2] = {0.f, 0.f};
  f32x4 accO[2][4] = {};
  char* Pw0 = &PT_lds[wv][0][0];
  char* Pw1 = &PT_lds[wv][1][0];

  // prologue
  u32 vreg[8];
  u64 bias_cur[8], bias_next[8];
  stageK(0, &K_lds[0][0]);
  loadV(0, vreg);
  loadBias(0, bias_cur);
  writeVT(vreg, &VT_lds[0][0]);
  loadV(1, vreg);

  for (int kt = 0; kt < 16; ++kt) {
    __syncthreads();
    char* Kc = &K_lds[kt & 1][0];
    char* Vc = &VT_lds[kt & 1][0];
    if (kt < 15) {
      writeVT(vreg, &VT_lds[(kt + 1) & 1][0]);
      stageK(kt + 1, &K_lds[(kt + 1) & 1][0]);
      loadBias(kt + 1, bias_next);
    }
    if (kt < 14) loadV(kt + 2, vreg);

    // ---- QK for both m, K-frags shared ----
    f32x4 s_[2][4];
    __builtin_amdgcn_s_setprio(1);
#pragma unroll
    for (int kf = 0; kf < 4; ++kf) {
      int row = kf * 16 + l16;
      short8 ak0 = *(const short8*)(Kc + row * 128 + ((g16 ^ l7) << 4));
      short8 ak1 = *(const short8*)(Kc + row * 128 + (((4 + g16) ^ l7) << 4));
#pragma unroll
      for (int m = 0; m < 2; ++m) {
        u64 bv = bias_cur[m * 4 + kf];
        u32 blo = (u32)bv, bhi = (u32)(bv >> 32);
        f32x4 acc;
        acc[0] = __uint_as_float(blo << 16);
        acc[1] = __uint_as_float(blo & 0xffff0000u);
        acc[2] = __uint_as_float(bhi << 16);
        acc[3] = __uint_as_float(bhi & 0xffff0000u);
        acc = __builtin_amdgcn_mfma_f32_16x16x32_bf16(ak0, b_q[m][0], acc, 0, 0, 0);
        acc = __builtin_amdgcn_mfma_f32_16x16x32_bf16(ak1, b_q[m][1], acc, 0, 0, 0);
        s_[m][kf] = acc;
      }
    }
    __builtin_amdgcn_s_setprio(0);

    // ---- static-max softmax: p = exp2(S'-16), lane-partial sums only ----
#pragma unroll
    for (int m = 0; m < 2; ++m) {
      char* Pw = (m == 0) ? Pw0 : Pw1;
      float sum = 0.f;
#pragma unroll
      for (int kf = 0; kf < 4; ++kf) {
        float e0 = __builtin_amdgcn_exp2f(s_[m][kf][0] - FIXED_MAX);
        float e1 = __builtin_amdgcn_exp2f(s_[m][kf][1] - FIXED_MAX);
        float e2 = __builtin_amdgcn_exp2f(s_[m][kf][2] - FIXED_MAX);
        float e3 = __builtin_amdgcn_exp2f(s_[m][kf][3] - FIXED_MAX);
        sum += (e0 + e1) + (e2 + e3);
        int chunk = kf * 2 + (g16 >> 1);
        int off = l16 * 128 + ((chunk ^ l7) << 4) + (g16 & 1) * 8;
        u32 c0 = cvtpk(e0, e1);
        u32 c1 = cvtpk(e2, e3);
        *(u64*)(Pw + off) = (u64)c0 | ((u64)c1 << 32);
      }
      lL[m] += sum;
    }

    // ---- PV: V-frags shared across m ----
    short8 b_p[2][2];
#pragma unroll
    for (int kc = 0; kc < 2; ++kc) {
      b_p[0][kc] = *(const short8*)(Pw0 + l16 * 128 + (((kc * 4 + g16) ^ l7) << 4));
      b_p[1][kc] = *(const short8*)(Pw1 + l16 * 128 + (((kc * 4 + g16) ^ l7) << 4));
    }
    __builtin_amdgcn_s_setprio(1);
#pragma unroll
    for (int f = 0; f < 4; ++f) {
      int vrow = f * 16 + l16;
      short8 av0 = *(const short8*)(Vc + vrow * 128 + ((g16 ^ l7) << 4));
      short8 av1 = *(const short8*)(Vc + vrow * 128 + (((4 + g16) ^ l7) << 4));
#pragma unroll
      for (int m = 0; m < 2; ++m) {
        accO[m][f] = __builtin_amdgcn_mfma_f32_16x16x32_bf16(av0, b_p[m][0], accO[m][f], 0, 0, 0);
        accO[m][f] = __builtin_amdgcn_mfma_f32_16x16x32_bf16(av1, b_p[m][1], accO[m][f], 0, 0, 0);
      }
    }
    __builtin_amdgcn_s_setprio(0);

    if (kt < 15) {
#pragma unroll
      for (int i = 0; i < 8; ++i) bias_cur[i] = bias_next[i];
    }
  }

  // epilogue: reduce l across g16 groups once; O = Qh + accO^T / l
#pragma unroll
  for (int m = 0; m < 2; ++m) {
    float l = lL[m];
    l += __shfl_xor(l, 16, 64);
    l += __shfl_xor(l, 32, 64);
    float inv = 1.0f / fmaxf(l, 1e-20f);
    int q = qbase + m * 16 + l16;
#pragma unroll
    for (int f = 0; f < 4; ++f) {
      size_t o = (batch_row + q) * DMODEL + hb + f * 16 + g16 * 4;
      u64 qh = *(const u64*)(Qp + o);
      u64 ov = 0;
#pragma unroll
      for (int r = 0; r < 4; ++r) {
        float val = accO[m][f][r] * inv + bf2f((u16)(qh >> (r * 16)));
        ov |= ((u64)f2bf(val)) << (r * 16);
      }
      *(u64*)(O1 + o) = ov;
    }
  }
}

// ---------------------------------------------------------------------------
// layernorm: one wave per 512-ch row. OUTF=0 -> bf16 out, OUTF=1 -> fp32 out
// ---------------------------------------------------------------------------
template<int OUTF>
__global__ __launch_bounds__(256) void ln_kernel(
    const u16* __restrict__ X, const float* __restrict__ g, const float* __restrict__ bb,
    void* __restrict__ outv)
{
  const int tid = threadIdx.x;
  const int wv = tid >> 6, lane = tid & 63;
  const size_t row = (size_t)blockIdx.x * 4 + wv;
  short8 x8 = *(const short8*)(X + row * 512 + lane * 8);
  float xf[8];
  float s = 0.f, s2 = 0.f;
#pragma unroll
  for (int i = 0; i < 8; ++i) {
    xf[i] = bf2f((u16)x8[i]);
    s += xf[i];
    s2 += xf[i] * xf[i];
  }
#pragma unroll
  for (int d = 1; d < 64; d <<= 1) {
    s += __shfl_xor(s, d, 64);
    s2 += __shfl_xor(s2, d, 64);
  }
  float mu = s * (1.f / 512.f);
  float var = s2 * (1.f / 512.f) - mu * mu;
  float rs = rsqrtf(var + 1e-5f);
  float4 ga = *(const float4*)(g + lane * 8);
  float4 gb = *(const float4*)(g + lane * 8 + 4);
  float4 ba = *(const float4*)(bb + lane * 8);
  float4 bc = *(const float4*)(bb + lane * 8 + 4);
  float gv[8] = {ga.x, ga.y, ga.z, ga.w, gb.x, gb.y, gb.z, gb.w};
  float bv[8] = {ba.x, ba.y, ba.z, ba.w, bc.x, bc.y, bc.z, bc.w};
  float y[8];
#pragma unroll
  for (int i = 0; i < 8; ++i) y[i] = (xf[i] - mu) * rs * gv[i] + bv[i];
  if (OUTF) {
    float* o = (float*)outv + row * 512 + lane * 8;
    float4 o1 = {y[0], y[1], y[2], y[3]};
    float4 o2 = {y[4], y[5], y[6], y[7]};
    *(float4*)o = o1;
    *(float4*)(o + 4) = o2;
  } else {
    short8 o;
#pragma unroll
    for (int i = 0; i < 8; ++i) o[i] = (short)f2bf(y[i]);
    *(short8*)((u16*)outv + row * 512 + lane * 8) = o;
  }
}

// ---------------------------------------------------------------------------
extern "C" void kernel_launch(void* const* d_in, const int* in_sizes, int n_in,
                              void* d_out, int out_size, void* d_ws, size_t ws_size,
                              hipStream_t stream) {
  (void)in_sizes; (void)n_in; (void)out_size; (void)ws_size;
  const float* Q  = (const float*)d_in[0];
  const float* K  = (const float*)d_in[1];
  const float* Wq = (const float*)d_in[2];
  const float* bq = (const float*)d_in[3];
  const float* Wk = (const float*)d_in[4];
  const float* bk = (const float*)d_in[5];
  const float* Wv = (const float*)d_in[6];
  const float* bv = (const float*)d_in[7];
  const float* Wo = (const float*)d_in[8];
  const float* bo = (const float*)d_in[9];
  const float* g0 = (const float*)d_in[10];
  const float* b0 = (const float*)d_in[11];
  const float* g1 = (const float*)d_in[12];
  const float* b1 = (const float*)d_in[13];
  const int*   M  = (const int*)d_in[14];
  float* out = (float*)d_out;
  char* ws = (char*)d_ws;

  u16* Qbf = (u16*)(ws + O_QBF);
  u16* Kbf = (u16*)(ws + O_KBF);
  u16* Wb  = (u16*)(ws + O_WB);
  u16* Qp  = (u16*)(ws + O_QP);
  u16* Kp  = (u16*)(ws + O_KP);
  u16* Vp  = (u16*)(ws + O_VP);
  u16* Mbias = (u16*)d_out;  // 16.77 MB, exactly out-size; dead until ln1
  u16* O1  = Kbf;   // Kbf dead after gemm1
  u16* Xn  = Qp;    // Qp dead after attn
  u16* Z   = Qbf;   // Qbf dead after gemm1

  prep_kernel<<<6400, 256, 0, stream>>>(Q, K, Wq, Wk, Wv, Wo, M, Qbf, Kbf, Wb, Mbias);
  gemm_bt<0><<<dim3(64, 4, 3), 256, 0, stream>>>(Qbf, Kbf, Wb, bq, bk, bv, Qp, nullptr);
  attn_kernel<<<512, 256, 0, stream>>>(Qp, Kp, Vp, Mbias, O1);
  ln_kernel<0><<<2048, 256, 0, stream>>>(O1, g0, b0, (void*)Xn);
  gemm_bt<1><<<dim3(64, 4, 1), 256, 0, stream>>>(Xn, nullptr, Wb + 3 * 262144, bo,
                                                 nullptr, nullptr, Z, Xn);
  ln_kernel<1><<<2048, 256, 0, stream>>>(Z, g1, b1, (void*)out);
}